// Round 8
// baseline (25.514 us; speedup 1.0000x reference)
//
#include <hip/hip_runtime.h>
#include <math.h>
#include <stdint.h>

#define BLOCK 256
#define EPB 64        // elements per block in stage/conv kernel
#define TAPS 16
#define HALO (TAPS - 1)

__device__ __forceinline__ float eluf(float v) { return v > 0.0f ? v : expm1f(v); }
__device__ __forceinline__ float dot4(float4 a, float4 b) {
    return a.x * b.x + a.y * b.y + a.z * b.z + a.w * b.w;
}

// Kernel 1: global->LDS DMA stage (linear LDS dest, inverse-swizzled global src),
// then conv1 (4 threads/element) + conv2 via 4-lane shfl reduce -> s[b] (float2).
__global__ __launch_bounds__(BLOCK, 5) void NF_conv_kernel(
    const float* __restrict__ x,
    const float* __restrict__ w1, const float* __restrict__ b1,
    const float* __restrict__ w2, const float* __restrict__ b2,
    float2* __restrict__ s, int B)
{
    __shared__ float4 xs[EPB * 32];   // 32 KiB

    const int t = threadIdx.x;
    const int w = t >> 6;        // wave id
    const int l = t & 63;        // lane id
    const int b0 = blockIdx.x * EPB;
    const float4* xf4 = reinterpret_cast<const float4*>(x);
    const float4* w1v = reinterpret_cast<const float4*>(w1);

    const long gbase = (long)b0 * 32;

    if (b0 + EPB <= B) {
        // Each wave issues 8 DMA loads of 1 KB. LDS dest is linear
        // (base + lane*16); the read-side XOR swizzle is pre-applied to the
        // global source index (XOR is an involution; permutation stays inside
        // one 512 B element span, so coalescing is preserved).
#pragma unroll
        for (int kk = 0; kk < 8; ++kk) {
            const int k = w * 8 + kk;           // wave-uniform
            const int e = 2 * k + (l >> 5);     // local element of this lane
            const int i = (l & 31) ^ (e & 7);   // inverse-swizzled f4 index
            const float4* src = xf4 + gbase + (long)e * 32 + i;
            auto gsrc = (const __attribute__((address_space(1))) uint32_t*)src;
            auto ldst = (__attribute__((address_space(3))) uint32_t*)
                        (uintptr_t)(xs + k * 64);   // wave-uniform base
            __builtin_amdgcn_global_load_lds(gsrc, ldst, 16, 0, 0);
        }
    } else {
        // Tail fallback (not taken for B=200000): reg-staged with bounds.
        float4 tmp[8];
#pragma unroll
        for (int k = 0; k < 8; ++k) {
            int e = 8 * k + (t >> 5);
            tmp[k] = (b0 + e < B) ? xf4[gbase + k * 256 + t]
                                  : make_float4(0.f, 0.f, 0.f, 0.f);
        }
#pragma unroll
        for (int k = 0; k < 8; ++k) {
            int e = 8 * k + (t >> 5);
            int i = t & 31;
            xs[e * 32 + (i ^ (e & 7))] = tmp[k];
        }
    }
    __syncthreads();

    // ---- conv1 (thread (e,j) -> h_j) + conv2 via 4-lane reduce ----
    const int e = t >> 2;
    const int j = t & 3;
    float acc = b1[0];
#pragma unroll
    for (int c = 0; c < 2; ++c)
#pragma unroll
        for (int p = 0; p < 4; ++p)
            acc += dot4(xs[e * 32 + ((c * 16 + j * 4 + p) ^ (e & 7))], w1v[c * 4 + p]);
    float h = eluf(acc);

    float pr = h * w2[j];
    float pi = h * w2[4 + j];
    pr += __shfl_xor(pr, 1);  pr += __shfl_xor(pr, 2);
    pi += __shfl_xor(pi, 1);  pi += __shfl_xor(pi, 2);

    if (j == 0 && (b0 + e) < B) {
        float sr = eluf(pr + b2[0]);
        float si = eluf(pi + b2[1]);
        s[b0 + e] = make_float2(sr, si);
    }
}

// Kernel 2: 16-tap complex FIR along batch axis, s (float2) -> out (float2).
__global__ __launch_bounds__(BLOCK) void NF_fir_kernel(
    const float2* __restrict__ s,
    const float* __restrict__ tr, const float* __restrict__ ti,
    float2* __restrict__ out, int B)
{
    __shared__ float s_r[BLOCK + HALO];
    __shared__ float s_i[BLOCK + HALO];

    const int t = threadIdx.x;
    const long base = (long)blockIdx.x * BLOCK;
    const long b = base + t;

    if (t < HALO) {
        long hb = base - HALO + t;
        float2 v = (hb >= 0) ? s[hb] : make_float2(0.f, 0.f);
        s_r[t] = v.x;  s_i[t] = v.y;
    }
    {
        float2 v = (b < B) ? s[b] : make_float2(0.f, 0.f);
        s_r[HALO + t] = v.x;  s_i[HALO + t] = v.y;
    }
    __syncthreads();

    if (b < B) {
        float yr = 0.f, yi = 0.f;
#pragma unroll
        for (int jj = 0; jj < TAPS; ++jj) {
            float a = s_r[HALO + t - jj];
            float c = s_i[HALO + t - jj];
            float trj = tr[jj], tij = ti[jj];
            yr += a * trj - c * tij;
            yi += a * tij + c * trj;
        }
        out[b] = make_float2(yr, yi);
    }
}

extern "C" void kernel_launch(void* const* d_in, const int* in_sizes, int n_in,
                              void* d_out, int out_size, void* d_ws, size_t ws_size,
                              hipStream_t stream) {
    const float* x  = (const float*)d_in[0];
    const float* w1 = (const float*)d_in[1];
    const float* b1 = (const float*)d_in[2];
    const float* w2 = (const float*)d_in[3];
    const float* b2 = (const float*)d_in[4];
    const float* tr = (const float*)d_in[5];
    const float* ti = (const float*)d_in[6];
    float2* out = (float2*)d_out;

    const int B = in_sizes[0] / 128;       // x is (B, 2, 64)
    float2* s = (float2*)d_ws;             // B float2 = 1.6 MB scratch

    const int grid1 = (B + EPB - 1) / EPB;
    NF_conv_kernel<<<grid1, BLOCK, 0, stream>>>(x, w1, b1, w2, b2, s, B);

    const int grid2 = (B + BLOCK - 1) / BLOCK;
    NF_fir_kernel<<<grid2, BLOCK, 0, stream>>>(s, tr, ti, out, B);
}

// Round 9
// 24.030 us; speedup vs baseline: 1.0617x; 1.0617x over previous
//
#include <hip/hip_runtime.h>
#include <math.h>

#define BLOCK 1024
#define EPB 256       // batch elements per block
#define TAPS 16
#define HWIN 16       // halo window (15 used + 1 pad)

__device__ __forceinline__ float eluf(float v) { return v > 0.f ? v : expm1f(v); }
__device__ __forceinline__ float dot4(float4 a, float4 b) {
    return a.x * b.x + a.y * b.y + a.z * b.z + a.w * b.w;
}

// Cooperative 4-lane conv1+conv2 for batch element ge (must be valid).
// Lane role j = t&3. Iteration p: lane loads float4 #(4p+j) of the element, so
// the 4 lanes of an element cover one contiguous 64B line per iteration ->
// a wave instruction touches exactly 16 full 64B lines (coalescing optimum).
// f4 index n = 4p+j: channel c = p>>2, conv1 output k = p&3, weight = w1v[c*4+j].
__device__ __forceinline__ void conv_elem(const float4* __restrict__ xf4, long ge,
        int j, float4 wv0, float4 wv1, float b1s,
        const float* __restrict__ w2, float b20, float b21,
        float& sr, float& si)
{
    const float4* base = xf4 + ge * 32;
    float4 v[8];
#pragma unroll
    for (int p = 0; p < 8; ++p) v[p] = base[4 * p + j];

    float a0 = 0.f, a1 = 0.f, a2 = 0.f, a3 = 0.f;
    a0 += dot4(v[0], wv0); a1 += dot4(v[1], wv0); a2 += dot4(v[2], wv0); a3 += dot4(v[3], wv0);
    a0 += dot4(v[4], wv1); a1 += dot4(v[5], wv1); a2 += dot4(v[6], wv1); a3 += dot4(v[7], wv1);

    // 4-lane butterfly: every lane ends with the full h sums
    a0 += __shfl_xor(a0, 1); a1 += __shfl_xor(a1, 1);
    a2 += __shfl_xor(a2, 1); a3 += __shfl_xor(a3, 1);
    a0 += __shfl_xor(a0, 2); a1 += __shfl_xor(a1, 2);
    a2 += __shfl_xor(a2, 2); a3 += __shfl_xor(a3, 2);

    float h0 = eluf(a0 + b1s), h1 = eluf(a1 + b1s);
    float h2 = eluf(a2 + b1s), h3 = eluf(a3 + b1s);

    float pr = b20 + h0 * w2[0] + h1 * w2[1] + h2 * w2[2] + h3 * w2[3];
    float pi = b21 + h0 * w2[4] + h1 * w2[5] + h2 * w2[6] + h3 * w2[7];
    sr = eluf(pr);
    si = eluf(pi);
}

__global__ __launch_bounds__(BLOCK, 4) void NF_20581483282566_kernel(
    const float* __restrict__ x,
    const float* __restrict__ w1, const float* __restrict__ b1,
    const float* __restrict__ w2, const float* __restrict__ b2,
    const float* __restrict__ tr, const float* __restrict__ ti,
    float2* __restrict__ out, int B)
{
    __shared__ float s_r[HWIN + EPB];
    __shared__ float s_i[HWIN + EPB];

    const int t = threadIdx.x;
    const int j = t & 3;
    const int e_loc = t >> 2;                 // 0..255
    const long b0 = (long)blockIdx.x * EPB;
    const long ge = b0 + e_loc;

    const float4* xf4 = reinterpret_cast<const float4*>(x);
    const float4* w1v = reinterpret_cast<const float4*>(w1);
    const float4 wv0 = w1v[j];        // c=0 weights for this lane role
    const float4 wv1 = w1v[4 + j];    // c=1
    const float b1s = b1[0];
    const float b20 = b2[0], b21 = b2[1];

    // ---- main elements: 256 per block, 4 lanes each ----
    if (ge < B) {
        float sr, si;
        conv_elem(xf4, ge, j, wv0, wv1, b1s, w2, b20, b21, sr, si);
        if (j == 0) { s_r[HWIN + e_loc] = sr; s_i[HWIN + e_loc] = si; }
    }

    // ---- halo: previous 16 elements (15 used), recomputed by wave 0 ----
    if (t < 4 * HWIN) {
        const int eh = t >> 2;                // 0..15
        const long he = b0 - HWIN + eh;
        float sr = 0.f, si = 0.f;
        if (he >= 0)
            conv_elem(xf4, he, j, wv0, wv1, b1s, w2, b20, b21, sr, si);
        if (j == 0) { s_r[eh] = sr; s_i[eh] = si; }
    }
    __syncthreads();

    // ---- 16-tap complex FIR along the batch axis ----
    if (t < EPB) {
        const long b = b0 + t;
        if (b < B) {
            float yr = 0.f, yi = 0.f;
#pragma unroll
            for (int jj = 0; jj < TAPS; ++jj) {
                float a = s_r[HWIN + t - jj];
                float c = s_i[HWIN + t - jj];
                float trj = tr[jj], tij = ti[jj];
                yr += a * trj - c * tij;
                yi += a * tij + c * trj;
            }
            out[b] = make_float2(yr, yi);
        }
    }
}

extern "C" void kernel_launch(void* const* d_in, const int* in_sizes, int n_in,
                              void* d_out, int out_size, void* d_ws, size_t ws_size,
                              hipStream_t stream) {
    const float* x  = (const float*)d_in[0];
    const float* w1 = (const float*)d_in[1];
    const float* b1 = (const float*)d_in[2];
    const float* w2 = (const float*)d_in[3];
    const float* b2 = (const float*)d_in[4];
    const float* tr = (const float*)d_in[5];
    const float* ti = (const float*)d_in[6];
    float2* out = (float2*)d_out;

    const int B = in_sizes[0] / 128;   // x is (B, 2, 64)
    const int grid = (B + EPB - 1) / EPB;
    NF_20581483282566_kernel<<<grid, BLOCK, 0, stream>>>(x, w1, b1, w2, b2, tr, ti, out, B);
}

// Round 10
// 23.738 us; speedup vs baseline: 1.0748x; 1.0123x over previous
//
#include <hip/hip_runtime.h>
#include <math.h>

#define BLOCK 1024
#define EPB 240       // batch elements per block (waves 0-14)
#define TAPS 16
#define HWIN 16       // halo window: 16 elems handled by wave 15 (15 used + 1 pad)

__device__ __forceinline__ float eluf(float v) { return v > 0.f ? v : expm1f(v); }
__device__ __forceinline__ float dot4(float4 a, float4 b) {
    return a.x * b.x + a.y * b.y + a.z * b.z + a.w * b.w;
}

// Cooperative 4-lane conv1+conv2 for batch element ge (must be valid).
// Lane role j = t&3. Iteration p: lane loads float4 #(4p+j) of the element, so
// the 4 lanes of an element cover one contiguous 64B line per iteration ->
// a wave instruction touches exactly 16 full 64B lines (coalescing optimum).
// channel c = p>>2, conv1 output k = p&3, weight f4 = w1v[c*4+j].
__device__ __forceinline__ void conv_elem(const float4* __restrict__ xf4, long ge,
        int j, float4 wv0, float4 wv1, float b1s,
        const float* __restrict__ w2, float b20, float b21,
        float& sr, float& si)
{
    const float4* base = xf4 + ge * 32;
    float4 v[8];
#pragma unroll
    for (int p = 0; p < 8; ++p) v[p] = base[4 * p + j];

    float a0 = 0.f, a1 = 0.f, a2 = 0.f, a3 = 0.f;
    a0 += dot4(v[0], wv0); a1 += dot4(v[1], wv0); a2 += dot4(v[2], wv0); a3 += dot4(v[3], wv0);
    a0 += dot4(v[4], wv1); a1 += dot4(v[5], wv1); a2 += dot4(v[6], wv1); a3 += dot4(v[7], wv1);

    // 4-lane butterfly: every lane ends with the full h sums
    a0 += __shfl_xor(a0, 1); a1 += __shfl_xor(a1, 1);
    a2 += __shfl_xor(a2, 1); a3 += __shfl_xor(a3, 1);
    a0 += __shfl_xor(a0, 2); a1 += __shfl_xor(a1, 2);
    a2 += __shfl_xor(a2, 2); a3 += __shfl_xor(a3, 2);

    float h0 = eluf(a0 + b1s), h1 = eluf(a1 + b1s);
    float h2 = eluf(a2 + b1s), h3 = eluf(a3 + b1s);

    float pr = b20 + h0 * w2[0] + h1 * w2[1] + h2 * w2[2] + h3 * w2[3];
    float pi = b21 + h0 * w2[4] + h1 * w2[5] + h2 * w2[6] + h3 * w2[7];
    sr = eluf(pr);
    si = eluf(pi);
}

__global__ __launch_bounds__(BLOCK, 4) void NF_20581483282566_kernel(
    const float* __restrict__ x,
    const float* __restrict__ w1, const float* __restrict__ b1,
    const float* __restrict__ w2, const float* __restrict__ b2,
    const float* __restrict__ tr, const float* __restrict__ ti,
    float2* __restrict__ out, int B)
{
    __shared__ float s_r[HWIN + EPB];
    __shared__ float s_i[HWIN + EPB];

    const int t = threadIdx.x;
    const int j = t & 3;
    const long b0 = (long)blockIdx.x * EPB;

    const float4* xf4 = reinterpret_cast<const float4*>(x);
    const float4* w1v = reinterpret_cast<const float4*>(w1);
    const float4 wv0 = w1v[j];        // c=0 weights for this lane role
    const float4 wv1 = w1v[4 + j];    // c=1
    const float b1s = b1[0];
    const float b20 = b2[0], b21 = b2[1];

    if (t < 4 * EPB) {
        // ---- main elements: waves 0-14, 4 lanes per element ----
        const int e_loc = t >> 2;             // 0..239
        const long ge = b0 + e_loc;
        if (ge < B) {
            float sr, si;
            conv_elem(xf4, ge, j, wv0, wv1, b1s, w2, b20, b21, sr, si);
            if (j == 0) { s_r[HWIN + e_loc] = sr; s_i[HWIN + e_loc] = si; }
        }
    } else {
        // ---- halo: wave 15 only (64 lanes = 16 elements), issues its loads
        //      concurrently with the main waves -> no serialized 2nd trip ----
        const int eh = (t - 4 * EPB) >> 2;    // 0..15
        const long he = b0 - HWIN + eh;
        float sr = 0.f, si = 0.f;
        if (he >= 0)
            conv_elem(xf4, he, j, wv0, wv1, b1s, w2, b20, b21, sr, si);
        if (j == 0) { s_r[eh] = sr; s_i[eh] = si; }
    }
    __syncthreads();

    // ---- 16-tap complex FIR along the batch axis ----
    if (t < EPB) {
        const long b = b0 + t;
        if (b < B) {
            float yr = 0.f, yi = 0.f;
#pragma unroll
            for (int jj = 0; jj < TAPS; ++jj) {
                float a = s_r[HWIN + t - jj];
                float c = s_i[HWIN + t - jj];
                float trj = tr[jj], tij = ti[jj];
                yr += a * trj - c * tij;
                yi += a * tij + c * trj;
            }
            out[b] = make_float2(yr, yi);
        }
    }
}

extern "C" void kernel_launch(void* const* d_in, const int* in_sizes, int n_in,
                              void* d_out, int out_size, void* d_ws, size_t ws_size,
                              hipStream_t stream) {
    const float* x  = (const float*)d_in[0];
    const float* w1 = (const float*)d_in[1];
    const float* b1 = (const float*)d_in[2];
    const float* w2 = (const float*)d_in[3];
    const float* b2 = (const float*)d_in[4];
    const float* tr = (const float*)d_in[5];
    const float* ti = (const float*)d_in[6];
    float2* out = (float2*)d_out;

    const int B = in_sizes[0] / 128;   // x is (B, 2, 64)
    const int grid = (B + EPB - 1) / EPB;
    NF_20581483282566_kernel<<<grid, BLOCK, 0, stream>>>(x, w1, b1, w2, b2, tr, ti, out, B);
}

// Round 11
// 23.310 us; speedup vs baseline: 1.0946x; 1.0184x over previous
//
#include <hip/hip_runtime.h>
#include <math.h>

#define BLOCK 1024
#define EPB 240       // batch elements per block (waves 0-14)
#define TAPS 16
#define HWIN 16       // halo window: 16 elems handled by wave 15 (15 used + 1 pad)

__device__ __forceinline__ float eluf(float v) { return v > 0.f ? v : expm1f(v); }
__device__ __forceinline__ float dot4(float4 a, float4 b) {
    return a.x * b.x + a.y * b.y + a.z * b.z + a.w * b.w;
}

// Cooperative 4-lane conv1+conv2 for batch element ge (must be valid).
// Lane role j = t&3; iteration p loads float4 #(4p+j) so the element's 4 lanes
// cover one contiguous 64B line -> wave instr touches 16 full lines.
// Loads are issued in 2 batches of 4 to keep live data regs at 16 VGPR
// (occupancy target: VGPR<=64 -> 2 blocks/CU).
__device__ __forceinline__ void conv_elem(const float4* __restrict__ xf4, long ge,
        int j, float4 wv0, float4 wv1, float b1s,
        const float* __restrict__ w2, float b20, float b21,
        float& sr, float& si)
{
    const float4* base = xf4 + ge * 32;
    float4 v0 = base[j],      v1 = base[4 + j],
           v2 = base[8 + j],  v3 = base[12 + j];
    float a0 = dot4(v0, wv0), a1 = dot4(v1, wv0),
          a2 = dot4(v2, wv0), a3 = dot4(v3, wv0);
    v0 = base[16 + j]; v1 = base[20 + j]; v2 = base[24 + j]; v3 = base[28 + j];
    a0 += dot4(v0, wv1); a1 += dot4(v1, wv1);
    a2 += dot4(v2, wv1); a3 += dot4(v3, wv1);

    // 4-lane butterfly: every lane ends with the full h sums
    a0 += __shfl_xor(a0, 1); a1 += __shfl_xor(a1, 1);
    a2 += __shfl_xor(a2, 1); a3 += __shfl_xor(a3, 1);
    a0 += __shfl_xor(a0, 2); a1 += __shfl_xor(a1, 2);
    a2 += __shfl_xor(a2, 2); a3 += __shfl_xor(a3, 2);

    float h0 = eluf(a0 + b1s), h1 = eluf(a1 + b1s);
    float h2 = eluf(a2 + b1s), h3 = eluf(a3 + b1s);

    float pr = b20 + h0 * w2[0] + h1 * w2[1] + h2 * w2[2] + h3 * w2[3];
    float pi = b21 + h0 * w2[4] + h1 * w2[5] + h2 * w2[6] + h3 * w2[7];
    sr = eluf(pr);
    si = eluf(pi);
}

__global__ __launch_bounds__(BLOCK, 8) void NF_20581483282566_kernel(
    const float* __restrict__ x,
    const float* __restrict__ w1, const float* __restrict__ b1,
    const float* __restrict__ w2, const float* __restrict__ b2,
    const float* __restrict__ tr, const float* __restrict__ ti,
    float2* __restrict__ out, int B)
{
    __shared__ float s_r[HWIN + EPB];
    __shared__ float s_i[HWIN + EPB];

    const int t = threadIdx.x;
    const int j = t & 3;
    const long b0 = (long)blockIdx.x * EPB;

    const float4* xf4 = reinterpret_cast<const float4*>(x);
    const float4* w1v = reinterpret_cast<const float4*>(w1);
    const float4 wv0 = w1v[j];        // c=0 weights for this lane role
    const float4 wv1 = w1v[4 + j];    // c=1
    const float b1s = b1[0];
    const float b20 = b2[0], b21 = b2[1];

    if (t < 4 * EPB) {
        // ---- main elements: waves 0-14, 4 lanes per element ----
        const int e_loc = t >> 2;             // 0..239
        const long ge = b0 + e_loc;
        if (ge < B) {
            float sr, si;
            conv_elem(xf4, ge, j, wv0, wv1, b1s, w2, b20, b21, sr, si);
            if (j == 0) { s_r[HWIN + e_loc] = sr; s_i[HWIN + e_loc] = si; }
        }
    } else {
        // ---- halo: wave 15 (16 elements), loads issued concurrently ----
        const int eh = (t - 4 * EPB) >> 2;    // 0..15
        const long he = b0 - HWIN + eh;
        float sr = 0.f, si = 0.f;
        if (he >= 0)
            conv_elem(xf4, he, j, wv0, wv1, b1s, w2, b20, b21, sr, si);
        if (j == 0) { s_r[eh] = sr; s_i[eh] = si; }
    }
    __syncthreads();

    // ---- 16-tap complex FIR along the batch axis ----
    if (t < EPB) {
        const long b = b0 + t;
        if (b < B) {
            float yr = 0.f, yi = 0.f;
#pragma unroll
            for (int jj = 0; jj < TAPS; ++jj) {
                float a = s_r[HWIN + t - jj];
                float c = s_i[HWIN + t - jj];
                float trj = tr[jj], tij = ti[jj];
                yr += a * trj - c * tij;
                yi += a * tij + c * trj;
            }
            out[b] = make_float2(yr, yi);
        }
    }
}

extern "C" void kernel_launch(void* const* d_in, const int* in_sizes, int n_in,
                              void* d_out, int out_size, void* d_ws, size_t ws_size,
                              hipStream_t stream) {
    const float* x  = (const float*)d_in[0];
    const float* w1 = (const float*)d_in[1];
    const float* b1 = (const float*)d_in[2];
    const float* w2 = (const float*)d_in[3];
    const float* b2 = (const float*)d_in[4];
    const float* tr = (const float*)d_in[5];
    const float* ti = (const float*)d_in[6];
    float2* out = (float2*)d_out;

    const int B = in_sizes[0] / 128;   // x is (B, 2, 64)
    const int grid = (B + EPB - 1) / EPB;
    NF_20581483282566_kernel<<<grid, BLOCK, 0, stream>>>(x, w1, b1, w2, b2, tr, ti, out, B);
}